// Round 11
// baseline (675.391 us; speedup 1.0000x reference)
//
#include <hip/hip_runtime.h>
#include <math.h>

// ---------------------------------------------------------------------------
// R25: mega-kernel with MANUAL grid barrier (no cooperative API — R24's
// hipLaunchCooperativeKernel poisoned the harness's graph capture and the
// fallback launches died capture-invalidated). 5 per-stage counters in d_ws,
// zeroed by a hipMemsetAsync node each replay; barrier = threadfence(release)
// + atomicAdd + agent-scope spin to 512 + threadfence(acquire) — the same
// primitive grid.sync() is built on (handles cross-XCD L2 staleness).
// Residency proof: LDS 53.8KB -> >=2 blocks/CU, launch_bounds(256,2) caps
// VGPR<=256, grid=512 = exact capacity -> all blocks co-resident, no deadlock.
// Conv bodies stay __device__ __noinline__ (R22 codegen isolation).
// ---------------------------------------------------------------------------

typedef __attribute__((ext_vector_type(8))) short bf16x8;
typedef __attribute__((ext_vector_type(4))) float f32x4;

__device__ inline float bf2f(unsigned short u) {
    unsigned v = ((unsigned)u) << 16;
    return __builtin_bit_cast(float, v);
}
__device__ inline unsigned short f2bf(float f) {
    unsigned u = __builtin_bit_cast(unsigned, f);
    u += 0x7FFF + ((u >> 16) & 1);   // RNE
    return (unsigned short)(u >> 16);
}

// ---- manual grid barrier (one unique counter per barrier per launch) -------
__device__ inline void grid_barrier(unsigned* ctr) {
    __syncthreads();
    if (threadIdx.x == 0) {
        __threadfence();                       // release: wbl2 agent-scope
        atomicAdd(ctr, 1u);
        while (__hip_atomic_load(ctr, __ATOMIC_RELAXED,
                                 __HIP_MEMORY_SCOPE_AGENT) < 512u)
            __builtin_amdgcn_s_sleep(2);
        __threadfence();                       // acquire: inv L1/L2
    }
    __syncthreads();
}

// ---------------- prep units ------------------------------------------------
__device__ void head_unit(float* scratch, int u,
    const float* __restrict__ x, const float* __restrict__ wh,
    const float* __restrict__ bh, unsigned short* __restrict__ fb0)
{
    __syncthreads();                     // scratch reuse barrier
    float* wlds = scratch;               // 216
    float* tile = scratch + 216;         // 3 * 1156
    const int tid = threadIdx.x;
    const int bx = u & 15, cog = (u >> 4) & 15, b = u >> 8;
    const int tile_y = (bx >> 2) * 32, tile_x = (bx & 3) * 32;

    if (tid < 216) {
        int co = tid & 7, rest = tid >> 3, tap = rest % 9, ci = rest / 9;
        wlds[tid] = wh[((cog * 8 + co) * 3 + ci) * 9 + tap];
    }
    for (int idx = tid; idx < 3 * 34 * 34; idx += 256) {
        int ci = idx / 1156, rem = idx - ci * 1156;
        int rr = rem / 34, c = rem - rr * 34;
        int gy = tile_y - 1 + rr, gx = tile_x - 1 + c;
        float v = 0.f;
        if ((unsigned)gy < 128u && (unsigned)gx < 128u)
            v = x[(((size_t)(b * 3 + ci)) << 14) + (gy << 7) + gx];
        tile[ci * 1156 + rem] = v;
    }
    __syncthreads();

    const int ty = tid >> 4, tx = tid & 15, py = ty * 2;
    float acc[2][2][8];
    #pragma unroll
    for (int r = 0; r < 2; ++r)
        #pragma unroll
        for (int h = 0; h < 2; ++h)
            #pragma unroll
            for (int co = 0; co < 8; ++co) acc[r][h][co] = 0.f;

    #pragma unroll
    for (int ci = 0; ci < 3; ++ci) {
        #pragma unroll
        for (int ky = 0; ky < 3; ++ky) {
            #pragma unroll
            for (int kx = 0; kx < 3; ++kx) {
                const float* wp = wlds + (ci * 9 + ky * 3 + kx) * 8;
                float i00 = tile[ci * 1156 + (py + ky) * 34 + tx + kx];
                float i01 = tile[ci * 1156 + (py + ky) * 34 + tx + 16 + kx];
                float i10 = tile[ci * 1156 + (py + 1 + ky) * 34 + tx + kx];
                float i11 = tile[ci * 1156 + (py + 1 + ky) * 34 + tx + 16 + kx];
                #pragma unroll
                for (int co = 0; co < 8; ++co) {
                    float wv = wp[co];
                    acc[0][0][co] += i00 * wv;
                    acc[0][1][co] += i01 * wv;
                    acc[1][0][co] += i10 * wv;
                    acc[1][1][co] += i11 * wv;
                }
            }
        }
    }

    #pragma unroll
    for (int r = 0; r < 2; ++r) {
        #pragma unroll
        for (int h = 0; h < 2; ++h) {
            int gy = tile_y + py + r, gx = tile_x + tx + h * 16;
            bf16x8 pv;
            #pragma unroll
            for (int co = 0; co < 8; ++co)
                pv[co] = (short)f2bf(acc[r][h][co] + bh[cog * 8 + co]);
            *(bf16x8*)(fb0 + (((((size_t)b << 14) + gy * 128 + gx)) << 7) + cog * 8) = pv;
        }
    }
}

__device__ void wtrans_unit(float* scratch, int r,
    const float* __restrict__ w0, const float* __restrict__ w1,
    const float* __restrict__ w2, const float* __restrict__ w3,
    const float* __restrict__ w4,
    unsigned short* __restrict__ t0, unsigned short* __restrict__ t1,
    unsigned short* __restrict__ t2, unsigned short* __restrict__ t3,
    unsigned short* __restrict__ t4)
{
    __syncthreads();                     // scratch reuse barrier
    const int tid = threadIdx.x;
    const float* w;
    unsigned short* t;
    int Coutp, Co, co0;
    if (r < 64) {
        int m = r >> 4;
        co0 = (r & 15) * 8;
        w = m == 0 ? w0 : m == 1 ? w1 : m == 2 ? w2 : w3;
        t = m == 0 ? t0 : m == 1 ? t1 : m == 2 ? t2 : t3;
        Coutp = 128; Co = 128;
    } else {
        co0 = (r - 64) * 8;
        w = w4; t = t4; Coutp = 80; Co = 72;
    }
    const float4* src = (const float4*)(w + (size_t)co0 * 1152);
    for (int i = tid; i < 2304; i += 256) {
        float4 v = {0.f, 0.f, 0.f, 0.f};
        int co_off = (i * 4) / 1152;
        if (co0 + co_off < Co) v = src[i];
        ((float4*)scratch)[i] = v;
    }
    __syncthreads();
    const int co = (tid >> 5) & 7, ch32 = tid & 31;
    #pragma unroll
    for (int tap = 0; tap < 9; ++tap)
        #pragma unroll
        for (int kc = 0; kc < 4; ++kc)
            t[((size_t)(tap * 4 + kc) * Coutp + co0 + co) * 32 + ch32] =
                f2bf(scratch[(co * 128 + kc * 32 + ch32) * 9 + tap]);
}

__device__ void kb_meanz_unit(const float* __restrict__ kern,
    unsigned short* __restrict__ kb, float* __restrict__ meanz)
{
    const int tid = threadIdx.x;
    for (int idx = tid; idx < 3072; idx += 256) {
        int lq = (idx & 31) >> 3, j = idx & 7;
        int row = idx >> 5;
        int li = row & 15, snt = row >> 4;
        int s = snt >> 1, nt = snt & 1;
        int co = s * 32 + lq * 8 + j, i = nt * 16 + li;
        float v = (co < 72 && i < 25) ? kern[co * 25 + i] : 0.f;
        kb[idx] = f2bf(v);
    }
    for (int idx = tid; idx < 2048; idx += 256) meanz[idx] = 0.f;
}

// ---------------- main conv body (R14/R23 EXACT K-loop, noinline) -----------
template <int LM, int NTW, int WNSPLIT, int DOMEAN>
__device__ __noinline__ void conv_body(
    unsigned short* lds, int tile, int b,
    const unsigned short* __restrict__ in, const unsigned short* __restrict__ wT,
    size_t wstride, const float* __restrict__ bias, unsigned short* __restrict__ out,
    float* __restrict__ meanb, int Coutp, int Cout, int relu)
{
    const int tid = threadIdx.x;
    const int row0 = (tile >> 3) << 4;
    const int col0 = (tile & 7) << 4;
    const int l = tid & 63, wv = tid >> 6;
    const int li = l & 15, lq = l >> 4;
    const int m_base = WNSPLIT ? (wv >> 1) * LM : wv * LM;
    const int n_base = WNSPLIT ? (wv & 1) * NTW : 0;
    const size_t inb = ((size_t)b) << 14;
    const unsigned short* wbase = wT + (size_t)b * wstride;

    f32x4 acc[LM][NTW];
    #pragma unroll
    for (int lm = 0; lm < LM; ++lm)
        #pragma unroll
        for (int nt = 0; nt < NTW; ++nt)
            acc[lm][nt] = (f32x4){0.f, 0.f, 0.f, 0.f};

    #pragma unroll 1
    for (int half = 0; half < 2; ++half) {
        __syncthreads();
        for (int u = tid; u < 2592; u += 256) {   // 324 px * 8 ch-groups
            int px = u >> 3, g = u & 7;
            int hr = px / 18, hc = px - hr * 18;
            int gy = row0 - 1 + hr, gx = col0 - 1 + hc;
            bf16x8 v = {0, 0, 0, 0, 0, 0, 0, 0};
            if ((unsigned)gy < 128u && (unsigned)gx < 128u)
                v = *(const bf16x8*)(in + ((inb + (gy << 7) + gx) << 7) + half * 64 + g * 8);
            int p = g ^ (px & 7);                 // XOR swizzle
            *(bf16x8*)(lds + px * 64 + p * 8) = v;
        }
        __syncthreads();

        auto loadB = [&](bf16x8 (&dst)[NTW], int s) {
            int tap = s >> 1, kcl = s & 1;
            const unsigned short* p = wbase +
                (size_t)(tap * 4 + half * 2 + kcl) * (Coutp * 32) +
                (n_base * 16 + li) * 32 + lq * 8;
            #pragma unroll
            for (int nt = 0; nt < NTW; ++nt)
                dst[nt] = *(const bf16x8*)(p + nt * 512);
        };
        auto compute = [&](bf16x8 (&bf)[NTW], int s) {
            int tap = s >> 1, kcl = s & 1;
            int ky = tap / 3, kx = tap - ky * 3;
            int g = kcl * 4 + lq;
            #pragma unroll
            for (int lm = 0; lm < LM; ++lm) {
                int px = (m_base + lm + ky) * 18 + li + kx;
                bf16x8 af = *(const bf16x8*)(lds + px * 64 + ((g ^ (px & 7)) * 8));
                #pragma unroll
                for (int nt = 0; nt < NTW; ++nt)
                    acc[lm][nt] = __builtin_amdgcn_mfma_f32_16x16x32_bf16(
                        af, bf[nt], acc[lm][nt], 0, 0, 0);
            }
        };

        bf16x8 bufA[NTW], bufB[NTW];
        loadB(bufA, 0);
        #pragma unroll 1
        for (int it = 0; it < 18; it += 2) {
            loadB(bufB, it + 1);
            compute(bufA, it);
            if (it + 2 < 18) loadB(bufA, it + 2);
            compute(bufB, it + 1);
        }
    }

    float bv[NTW], msum[NTW];
    #pragma unroll
    for (int nt = 0; nt < NTW; ++nt) {
        int co = (n_base + nt) * 16 + li;
        bv[nt] = (co < Cout) ? bias[co] : 0.f;
        msum[nt] = 0.f;
    }

    #pragma unroll
    for (int lm = 0; lm < LM; ++lm) {
        int row = row0 + m_base + lm;
        #pragma unroll
        for (int r = 0; r < 4; ++r) {
            int col = col0 + lq * 4 + r;
            size_t pbase = (inb + row * 128 + col) * (size_t)Coutp;
            #pragma unroll
            for (int nt = 0; nt < NTW; ++nt) {
                float v = acc[lm][nt][r] + bv[nt];
                if (relu) v = fmaxf(v, 0.f);
                if (DOMEAN) msum[nt] += v;
                out[pbase + (n_base + nt) * 16 + li] = f2bf(v);
            }
        }
    }
    if (DOMEAN) {
        #pragma unroll
        for (int nt = 0; nt < NTW; ++nt) {
            float t = msum[nt];
            t += __shfl_xor(t, 16, 64);
            t += __shfl_xor(t, 32, 64);
            if (lq == 0)
                atomicAdd(&meanb[b * 128 + (n_base + nt) * 16 + li], t);
        }
    }
}

// ---------------- SE-scaled conv body (noinline) ----------------------------
template <int LM, int NTW, int WNSPLIT, int TAILFUSE>
__device__ __noinline__ void conv_se_body(
    unsigned short* lds, float* slds, int tile, int b,
    const unsigned short* __restrict__ in, const unsigned short* __restrict__ wT,
    const float* __restrict__ bias, unsigned short* __restrict__ out,
    const float* __restrict__ se_mean,
    const float* __restrict__ sw1, const float* __restrict__ sb1,
    const float* __restrict__ sw2, const float* __restrict__ sb2,
    const float* __restrict__ x, const unsigned short* __restrict__ kb,
    float* __restrict__ outf, int Coutp, int Cout, int relu)
{
    const int tid = threadIdx.x;
    const int row0 = (tile >> 3) << 4;
    const int col0 = (tile & 7) << 4;
    const int l = tid & 63, wv = tid >> 6;
    const int li = l & 15, lq = l >> 4;
    const int m_base = WNSPLIT ? (wv >> 1) * LM : wv * LM;
    const int n_base = WNSPLIT ? (wv & 1) * NTW : 0;
    const size_t inb = ((size_t)b) << 14;
    const unsigned short* wbase = wT;

    // wave-parallel SE prologue: 8 groups of 32 lanes, one dot each
    {
        const int grp = tid >> 5, j = tid & 31;
        float4 wv4 = ((const float4*)(sw1 + grp * 128))[j];
        float4 mv4 = ((const float4*)(se_mean + b * 128))[j];
        float part = wv4.x * mv4.x + wv4.y * mv4.y + wv4.z * mv4.z + wv4.w * mv4.w;
        part += __shfl_xor(part, 1, 64);
        part += __shfl_xor(part, 2, 64);
        part += __shfl_xor(part, 4, 64);
        part += __shfl_xor(part, 8, 64);
        part += __shfl_xor(part, 16, 64);
        if (j == 0)
            slds[128 + grp] = fmaxf(part * (1.f / 16384.f) + sb1[grp], 0.f);
    }
    __syncthreads();
    if (tid < 128) {
        float s = sb2[tid];
        #pragma unroll
        for (int j = 0; j < 8; ++j) s += sw2[tid * 8 + j] * slds[128 + j];
        slds[tid] = 1.f / (1.f + expf(-s));
    }
    __syncthreads();

    f32x4 acc[LM][NTW];
    #pragma unroll
    for (int lm = 0; lm < LM; ++lm)
        #pragma unroll
        for (int nt = 0; nt < NTW; ++nt)
            acc[lm][nt] = (f32x4){0.f, 0.f, 0.f, 0.f};

    #pragma unroll 1
    for (int half = 0; half < 2; ++half) {
        float msc[8];
        #pragma unroll
        for (int j = 0; j < 8; ++j)
            msc[j] = slds[half * 64 + (tid & 7) * 8 + j];
        __syncthreads();
        for (int u = tid; u < 2592; u += 256) {   // 324 px * 8 ch-groups
            int px = u >> 3, g = u & 7;
            int hr = px / 18, hc = px - hr * 18;
            int gy = row0 - 1 + hr, gx = col0 - 1 + hc;
            bf16x8 v = {0, 0, 0, 0, 0, 0, 0, 0};
            if ((unsigned)gy < 128u && (unsigned)gx < 128u)
                v = *(const bf16x8*)(in + ((inb + (gy << 7) + gx) << 7) + half * 64 + g * 8);
            #pragma unroll
            for (int j = 0; j < 8; ++j)
                v[j] = (short)f2bf(bf2f((unsigned short)v[j]) * msc[j]);
            int p = g ^ (px & 7);                 // XOR swizzle
            *(bf16x8*)(lds + px * 64 + p * 8) = v;
        }
        __syncthreads();

        auto loadB = [&](bf16x8 (&dst)[NTW], int s) {
            int tap = s >> 1, kcl = s & 1;
            const unsigned short* p = wbase +
                (size_t)(tap * 4 + half * 2 + kcl) * (Coutp * 32) +
                (n_base * 16 + li) * 32 + lq * 8;
            #pragma unroll
            for (int nt = 0; nt < NTW; ++nt)
                dst[nt] = *(const bf16x8*)(p + nt * 512);
        };
        auto compute = [&](bf16x8 (&bf)[NTW], int s) {
            int tap = s >> 1, kcl = s & 1;
            int ky = tap / 3, kx = tap - ky * 3;
            int g = kcl * 4 + lq;
            #pragma unroll
            for (int lm = 0; lm < LM; ++lm) {
                int px = (m_base + lm + ky) * 18 + li + kx;
                bf16x8 af = *(const bf16x8*)(lds + px * 64 + ((g ^ (px & 7)) * 8));
                #pragma unroll
                for (int nt = 0; nt < NTW; ++nt)
                    acc[lm][nt] = __builtin_amdgcn_mfma_f32_16x16x32_bf16(
                        af, bf[nt], acc[lm][nt], 0, 0, 0);
            }
        };

        bf16x8 bufA[NTW], bufB[NTW];
        loadB(bufA, 0);
        #pragma unroll 1
        for (int it = 0; it < 18; it += 2) {
            loadB(bufB, it + 1);
            compute(bufA, it);
            if (it + 2 < 18) loadB(bufA, it + 2);
            compute(bufB, it + 1);
        }
    }

    float bv[NTW];
    #pragma unroll
    for (int nt = 0; nt < NTW; ++nt) {
        int co = (n_base + nt) * 16 + li;
        bv[nt] = (co < Cout) ? bias[co] : 0.f;
    }

    if (TAILFUSE) {
        // ---- P (wgt) -> LDS, stride 104 ush; zero pad co 80..95 ----
        __syncthreads();
        #pragma unroll
        for (int lm = 0; lm < LM; ++lm) {
            int rowl = m_base + lm;
            #pragma unroll
            for (int r = 0; r < 4; ++r) {
                int coll = lq * 4 + r;
                #pragma unroll
                for (int nt = 0; nt < NTW; ++nt)
                    lds[(rowl * 16 + coll) * 104 + nt * 16 + li] =
                        f2bf(acc[lm][nt][r] + bv[nt]);
            }
        }
        {
            bf16x8 z = {0, 0, 0, 0, 0, 0, 0, 0};
            *(bf16x8*)(lds + tid * 104 + 80) = z;
            *(bf16x8*)(lds + tid * 104 + 88) = z;
        }
        __syncthreads();

        // ---- e-GEMM: e[px][i] = sum_co P[px][co] * kern[co][i] ----
        f32x4 eacc[4][2];
        #pragma unroll
        for (int mm = 0; mm < 4; ++mm)
            #pragma unroll
            for (int nt = 0; nt < 2; ++nt)
                eacc[mm][nt] = (f32x4){0.f, 0.f, 0.f, 0.f};
        #pragma unroll
        for (int s = 0; s < 3; ++s) {
            bf16x8 kbf[2];
            #pragma unroll
            for (int nt = 0; nt < 2; ++nt)
                kbf[nt] = *(const bf16x8*)(kb + ((s * 2 + nt) * 16 + li) * 32 + lq * 8);
            #pragma unroll
            for (int mm = 0; mm < 4; ++mm) {
                int px = (wv * 4 + mm) * 16 + li;
                bf16x8 pf = *(const bf16x8*)(lds + px * 104 + s * 32 + lq * 8);
                #pragma unroll
                for (int nt = 0; nt < 2; ++nt)
                    eacc[mm][nt] = __builtin_amdgcn_mfma_f32_16x16x32_bf16(
                        pf, kbf[nt], eacc[mm][nt], 0, 0, 0);
            }
        }
        __syncthreads();

        // ---- e (C-layout) -> LDS fp32, stride 33 ----
        float* elds = (float*)lds;
        #pragma unroll
        for (int mm = 0; mm < 4; ++mm) {
            #pragma unroll
            for (int nt = 0; nt < 2; ++nt) {
                int i = nt * 16 + li;
                if (i < 25) {
                    #pragma unroll
                    for (int r = 0; r < 4; ++r) {
                        int px = (wv * 4 + mm) * 16 + lq * 4 + r;
                        elds[px * 33 + i] = eacc[mm][nt][r];
                    }
                }
            }
        }
        __syncthreads();

        // ---- apply ----
        const int h = row0 + (tid >> 4), w = col0 + (tid & 15);
        const int pix = h * 128 + w;
        float e[25];
        #pragma unroll
        for (int i = 0; i < 25; ++i) e[i] = elds[tid * 33 + i];

        int yy[5], xx[5];
        #pragma unroll
        for (int d = 0; d < 5; ++d) {
            int y = h - 2 + d;
            yy[d] = y < 0 ? -y : (y > 127 ? 254 - y : y);
            int xv = w - 2 + d;
            xx[d] = xv < 0 ? -xv : (xv > 127 ? 254 - xv : xv);
        }
        #pragma unroll
        for (int c = 0; c < 3; ++c) {
            const float* xc = x + ((size_t)(b * 3 + c) << 14);
            float s = 0.f;
            #pragma unroll
            for (int dy = 0; dy < 5; ++dy)
                #pragma unroll
                for (int dx = 0; dx < 5; ++dx)
                    s += e[dy * 5 + dx] * xc[yy[dy] * 128 + xx[dx]];
            outf[((size_t)(b * 3 + c) << 14) + pix] = s;
        }
        return;
    }

    #pragma unroll
    for (int lm = 0; lm < LM; ++lm) {
        int row = row0 + m_base + lm;
        #pragma unroll
        for (int r = 0; r < 4; ++r) {
            int col = col0 + lq * 4 + r;
            size_t pbase = (inb + row * 128 + col) * (size_t)Coutp;
            #pragma unroll
            for (int nt = 0; nt < NTW; ++nt) {
                float v = acc[lm][nt][r] + bv[nt];
                if (relu) v = fmaxf(v, 0.f);
                out[pbase + (n_base + nt) * 16 + li] = f2bf(v);
            }
        }
    }
}

// ---------------- mega kernel (manual grid barriers) ------------------------
__global__ __launch_bounds__(256, 2) void mega(
    const float* x, const float* wh, const float* bh,
    const float* w0, const float* w1, const float* w2, const float* w3,
    const float* w4, const float* kern,
    const float* b_h1a, const float* b_h1b, const float* b_h2a,
    const float* b_h2b, const float* b_tail,
    const float* du1_w1, const float* du1_b1, const float* du1_w2,
    const float* du1_b2, const float* du2_w1, const float* du2_b1,
    const float* du2_w2, const float* du2_b2,
    float* out, unsigned short* fb0, unsigned short* fb1,
    unsigned short* wt1, unsigned short* wt2, unsigned short* wt3,
    unsigned short* wt4, unsigned short* wtt, unsigned short* kbb,
    float* mean1, unsigned* bars)
{
    __shared__ unsigned short smem[26624];   // 53248 B (max: tail P-lds)
    __shared__ float slds[136];
    const int bid = blockIdx.x;
    float* scratch = (float*)smem;           // 36864 B needed by prep units
    float* mean2 = mean1 + 1024;

    // ---- stage 0: prep (head 2048 units, 4/block; wtrans+kb on 437..511) --
    #pragma unroll 1
    for (int i = 0; i < 4; ++i)
        head_unit(scratch, bid * 4 + i, x, wh, bh, fb0);
    if (bid >= 437) {
        int r = bid - 437;
        if (r < 74)
            wtrans_unit(scratch, r, w0, w1, w2, w3, w4, wt1, wt2, wt3, wt4, wtt);
        else
            kb_meanz_unit(kern, kbb, mean1);
    }
    grid_barrier(bars + 0);

    const int tile = bid & 63, b = bid >> 6;
    conv_body<8, 4, 1, 0>(smem, tile, b, fb0, wt1, 0, b_h1a, fb1, nullptr, 128, 128, 1);
    grid_barrier(bars + 1);
    conv_body<8, 4, 1, 1>(smem, tile, b, fb1, wt2, 0, b_h1b, fb0, mean1, 128, 128, 1);
    grid_barrier(bars + 2);
    conv_se_body<8, 4, 1, 0>(smem, slds, tile, b, fb0, wt3, b_h2a, fb1,
                             mean1, du1_w1, du1_b1, du1_w2, du1_b2,
                             nullptr, nullptr, nullptr, 128, 128, 1);
    grid_barrier(bars + 3);
    conv_body<8, 4, 1, 1>(smem, tile, b, fb1, wt4, 0, b_h2b, fb0, mean2, 128, 128, 1);
    grid_barrier(bars + 4);
    conv_se_body<4, 5, 0, 1>(smem, slds, tile, b, fb0, wtt, b_tail, nullptr,
                             mean2, du2_w1, du2_b1, du2_w2, du2_b2,
                             x, kbb, out, 80, 72, 0);
}

// ---------------------------------------------------------------------------
extern "C" void kernel_launch(void* const* d_in, const int* in_sizes, int n_in,
                              void* d_out, int out_size, void* d_ws, size_t ws_size,
                              hipStream_t stream)
{
    const float* x      = (const float*)d_in[0];
    const float* w_head = (const float*)d_in[1];
    const float* b_head = (const float*)d_in[2];
    const float* w_h1a  = (const float*)d_in[3];
    const float* b_h1a  = (const float*)d_in[4];
    const float* w_h1b  = (const float*)d_in[5];
    const float* b_h1b  = (const float*)d_in[6];
    const float* du1_w1 = (const float*)d_in[7];
    const float* du1_b1 = (const float*)d_in[8];
    const float* du1_w2 = (const float*)d_in[9];
    const float* du1_b2 = (const float*)d_in[10];
    const float* w_h2a  = (const float*)d_in[11];
    const float* b_h2a  = (const float*)d_in[12];
    const float* w_h2b  = (const float*)d_in[13];
    const float* b_h2b  = (const float*)d_in[14];
    const float* du2_w1 = (const float*)d_in[15];
    const float* du2_b1 = (const float*)d_in[16];
    const float* du2_w2 = (const float*)d_in[17];
    const float* du2_b2 = (const float*)d_in[18];
    const float* w_tail = (const float*)d_in[19];
    const float* b_tail = (const float*)d_in[20];
    const float* kern   = (const float*)d_in[21];
    float* out = (float*)d_out;

    unsigned short* fb0  = (unsigned short*)d_ws;        // 16,777,216 elems
    unsigned short* fb1  = fb0 + 16777216;
    unsigned short* wt1  = fb1 + 16777216;               // 147456 each
    unsigned short* wt2  = wt1 + 147456;
    unsigned short* wt3  = wt2 + 147456;
    unsigned short* wt4  = wt3 + 147456;
    unsigned short* wtt  = wt4 + 147456;                 // 92160
    unsigned short* kbb  = wtt + 92160;                  // 3072 (kern B-frag)
    float* mean1  = (float*)(kbb + 3072);                // 1024
    float* mean2  = mean1 + 1024;
    unsigned* bars = (unsigned*)(mean2 + 1024);          // 8 barrier counters

    // zero barrier counters (graph-capturable node, replayed every iteration)
    hipMemsetAsync((void*)bars, 0, 8 * sizeof(unsigned), stream);

    mega<<<dim3(512), dim3(256), 0, stream>>>(
        x, w_head, b_head, w_h1a, w_h1b, w_h2a, w_h2b, w_tail, kern,
        b_h1a, b_h1b, b_h2a, b_h2b, b_tail,
        du1_w1, du1_b1, du1_w2, du1_b2, du2_w1, du2_b1, du2_w2, du2_b2,
        out, fb0, fb1, wt1, wt2, wt3, wt4, wtt, kbb, mean1, bars);
}

// Round 12
// 320.358 us; speedup vs baseline: 2.1082x; 2.1082x over previous
//
#include <hip/hip_runtime.h>
#include <math.h>

// ---------------------------------------------------------------------------
// R26 = R23 verbatim (best passing, 318.8us). R24 (cooperative mega) broke
// graph capture; R25 (manual-barrier mega) paid a ~1.3KB/thread noinline-ABI
// scratch tax (WRITE 195->370MB, 2x dur) -- pre-committed failure signature,
// fusion line closed. Ledger: conv K-loop is a 6-for-6-defended local optimum;
// aux pool cut 102->79us; remaining ~55us is dispatch-boundary overhead with
// no harness-compatible reclamation mechanism.
// ---------------------------------------------------------------------------

typedef __attribute__((ext_vector_type(8))) short bf16x8;
typedef __attribute__((ext_vector_type(4))) float f32x4;

__device__ inline float bf2f(unsigned short u) {
    unsigned v = ((unsigned)u) << 16;
    return __builtin_bit_cast(float, v);
}
__device__ inline unsigned short f2bf(float f) {
    unsigned u = __builtin_bit_cast(unsigned, f);
    u += 0x7FFF + ((u >> 16) & 1);   // RNE
    return (unsigned short)(u >> 16);
}

// ---------------- prep: head conv (bid<2048) + weight transforms ------------
// bid < 2048          : head conv (bx = bid&15, cog = (bid>>4)&15, b = bid>>8)
// bid in [2048,2112)  : wt1..4 transpose, m = (bid-2048)>>4, co0 = ((bid-2048)&15)*8
// bid in [2112,2122)  : wtt transpose, co0 = (bid-2112)*8 (Co=72, zeros beyond)
// bid == 2122         : kb build + mean zeroing
__global__ __launch_bounds__(256) void prep(
    const float* __restrict__ x, const float* __restrict__ wh,
    const float* __restrict__ bh, unsigned short* __restrict__ fb0,
    const float* __restrict__ w0, const float* __restrict__ w1,
    const float* __restrict__ w2, const float* __restrict__ w3,
    const float* __restrict__ w4, const float* __restrict__ kern,
    unsigned short* __restrict__ t0, unsigned short* __restrict__ t1,
    unsigned short* __restrict__ t2, unsigned short* __restrict__ t3,
    unsigned short* __restrict__ t4, unsigned short* __restrict__ kb,
    float* __restrict__ meanz)
{
    __shared__ float scratch[9216];      // 36 KB: wtrans chunk / head tile+wlds
    const int tid = threadIdx.x;
    const int bid = blockIdx.x;

    if (bid >= 2048) {
        if (bid == 2122) {               // ---- kb + mean zeroing ----
            for (int idx = tid; idx < 3072; idx += 256) {
                int lq = (idx & 31) >> 3, j = idx & 7;
                int row = idx >> 5;
                int li = row & 15, snt = row >> 4;
                int s = snt >> 1, nt = snt & 1;
                int co = s * 32 + lq * 8 + j, i = nt * 16 + li;
                float v = (co < 72 && i < 25) ? kern[co * 25 + i] : 0.f;
                kb[idx] = f2bf(v);
            }
            for (int idx = tid; idx < 2048; idx += 256) meanz[idx] = 0.f;
            return;
        }
        // ---- coalesced weight transpose, 8-co chunk per block ----
        const float* w;
        unsigned short* t;
        int Coutp, Co, co0;
        if (bid < 2112) {
            int r = bid - 2048;
            int m = r >> 4;
            co0 = (r & 15) * 8;
            w = m == 0 ? w0 : m == 1 ? w1 : m == 2 ? w2 : w3;
            t = m == 0 ? t0 : m == 1 ? t1 : m == 2 ? t2 : t3;
            Coutp = 128; Co = 128;
        } else {
            co0 = (bid - 2112) * 8;
            w = w4; t = t4; Coutp = 80; Co = 72;
        }
        // stage w[co0..co0+8)[128ch][9taps] = 9216 floats, contiguous
        const float4* src = (const float4*)(w + (size_t)co0 * 1152);
        for (int i = tid; i < 2304; i += 256) {
            float4 v = {0.f, 0.f, 0.f, 0.f};
            int co_off = (i * 4) / 1152;
            if (co0 + co_off < Co) v = src[i];
            ((float4*)scratch)[i] = v;
        }
        __syncthreads();
        // write transposed: out[((tap*4+kc)*Coutp + co0+co)*32 + ch32]
        const int co = (tid >> 5) & 7, ch32 = tid & 31;
        #pragma unroll
        for (int tap = 0; tap < 9; ++tap)
            #pragma unroll
            for (int kc = 0; kc < 4; ++kc)
                t[((size_t)(tap * 4 + kc) * Coutp + co0 + co) * 32 + ch32] =
                    f2bf(scratch[(co * 128 + kc * 32 + ch32) * 9 + tap]);
        return;
    }

    // ---- head conv ----
    float* wlds = scratch;               // 216
    float* tile = scratch + 216;         // 3 * 1156
    const int bx = bid & 15, cog = (bid >> 4) & 15, b = bid >> 8;
    const int tile_y = (bx >> 2) * 32, tile_x = (bx & 3) * 32;

    if (tid < 216) {
        int co = tid & 7, rest = tid >> 3, tap = rest % 9, ci = rest / 9;
        wlds[tid] = wh[((cog * 8 + co) * 3 + ci) * 9 + tap];
    }
    for (int idx = tid; idx < 3 * 34 * 34; idx += 256) {
        int ci = idx / 1156, rem = idx - ci * 1156;
        int rr = rem / 34, c = rem - rr * 34;
        int gy = tile_y - 1 + rr, gx = tile_x - 1 + c;
        float v = 0.f;
        if ((unsigned)gy < 128u && (unsigned)gx < 128u)
            v = x[(((size_t)(b * 3 + ci)) << 14) + (gy << 7) + gx];
        tile[ci * 1156 + rem] = v;
    }
    __syncthreads();

    const int ty = tid >> 4, tx = tid & 15, py = ty * 2;
    float acc[2][2][8];
    #pragma unroll
    for (int r = 0; r < 2; ++r)
        #pragma unroll
        for (int h = 0; h < 2; ++h)
            #pragma unroll
            for (int co = 0; co < 8; ++co) acc[r][h][co] = 0.f;

    #pragma unroll
    for (int ci = 0; ci < 3; ++ci) {
        #pragma unroll
        for (int ky = 0; ky < 3; ++ky) {
            #pragma unroll
            for (int kx = 0; kx < 3; ++kx) {
                const float* wp = wlds + (ci * 9 + ky * 3 + kx) * 8;
                float i00 = tile[ci * 1156 + (py + ky) * 34 + tx + kx];
                float i01 = tile[ci * 1156 + (py + ky) * 34 + tx + 16 + kx];
                float i10 = tile[ci * 1156 + (py + 1 + ky) * 34 + tx + kx];
                float i11 = tile[ci * 1156 + (py + 1 + ky) * 34 + tx + 16 + kx];
                #pragma unroll
                for (int co = 0; co < 8; ++co) {
                    float wv = wp[co];
                    acc[0][0][co] += i00 * wv;
                    acc[0][1][co] += i01 * wv;
                    acc[1][0][co] += i10 * wv;
                    acc[1][1][co] += i11 * wv;
                }
            }
        }
    }

    #pragma unroll
    for (int r = 0; r < 2; ++r) {
        #pragma unroll
        for (int h = 0; h < 2; ++h) {
            int gy = tile_y + py + r, gx = tile_x + tx + h * 16;
            bf16x8 pv;
            #pragma unroll
            for (int co = 0; co < 8; ++co)
                pv[co] = (short)f2bf(acc[r][h][co] + bh[cog * 8 + co]);
            *(bf16x8*)(fb0 + (((((size_t)b << 14) + gy * 128 + gx)) << 7) + cog * 8) = pv;
        }
    }
}

// ---------------- main conv: implicit GEMM, bf16 MFMA (R14 EXACT) -----------
// Block: 16x16 px tile; A staged in two 64-ch halves, UNPADDED stride 64 ush
// with XOR swizzle (channel-group p = g ^ (px&7)) -> conflict-free b128 reads.
// WNSPLIT=1: 4 waves tile 2 m-groups x 2 n-groups (LM=8, NTW=4 for 128 co).
template <int LM, int NTW, int WNSPLIT, int DOMEAN>
__global__ __launch_bounds__(256, 2) void conv_mfma(
    const unsigned short* __restrict__ in, const unsigned short* __restrict__ wT,
    size_t wstride, const float* __restrict__ bias, unsigned short* __restrict__ out,
    float* __restrict__ meanb, const float* __restrict__ x,
    const unsigned short* __restrict__ kb, float* __restrict__ outf,
    int Coutp, int Cout, int relu)
{
    __shared__ unsigned short lds[20736];
    const int tid = threadIdx.x;
    const int b = blockIdx.y;
    const int row0 = (blockIdx.x >> 3) << 4;
    const int col0 = (blockIdx.x & 7) << 4;
    const int l = tid & 63, wv = tid >> 6;
    const int li = l & 15, lq = l >> 4;
    const int m_base = WNSPLIT ? (wv >> 1) * LM : wv * LM;
    const int n_base = WNSPLIT ? (wv & 1) * NTW : 0;
    const size_t inb = ((size_t)b) << 14;
    const unsigned short* wbase = wT + (size_t)b * wstride;

    f32x4 acc[LM][NTW];
    #pragma unroll
    for (int lm = 0; lm < LM; ++lm)
        #pragma unroll
        for (int nt = 0; nt < NTW; ++nt)
            acc[lm][nt] = (f32x4){0.f, 0.f, 0.f, 0.f};

    #pragma unroll 1
    for (int half = 0; half < 2; ++half) {
        __syncthreads();
        for (int u = tid; u < 2592; u += 256) {   // 324 px * 8 ch-groups
            int px = u >> 3, g = u & 7;
            int hr = px / 18, hc = px - hr * 18;
            int gy = row0 - 1 + hr, gx = col0 - 1 + hc;
            bf16x8 v = {0, 0, 0, 0, 0, 0, 0, 0};
            if ((unsigned)gy < 128u && (unsigned)gx < 128u)
                v = *(const bf16x8*)(in + ((inb + (gy << 7) + gx) << 7) + half * 64 + g * 8);
            int p = g ^ (px & 7);                 // XOR swizzle
            *(bf16x8*)(lds + px * 64 + p * 8) = v;
        }
        __syncthreads();

        auto loadB = [&](bf16x8 (&dst)[NTW], int s) {
            int tap = s >> 1, kcl = s & 1;
            const unsigned short* p = wbase +
                (size_t)(tap * 4 + half * 2 + kcl) * (Coutp * 32) +
                (n_base * 16 + li) * 32 + lq * 8;
            #pragma unroll
            for (int nt = 0; nt < NTW; ++nt)
                dst[nt] = *(const bf16x8*)(p + nt * 512);
        };
        auto compute = [&](bf16x8 (&bf)[NTW], int s) {
            int tap = s >> 1, kcl = s & 1;
            int ky = tap / 3, kx = tap - ky * 3;
            int g = kcl * 4 + lq;
            #pragma unroll
            for (int lm = 0; lm < LM; ++lm) {
                int px = (m_base + lm + ky) * 18 + li + kx;
                bf16x8 af = *(const bf16x8*)(lds + px * 64 + ((g ^ (px & 7)) * 8));
                #pragma unroll
                for (int nt = 0; nt < NTW; ++nt)
                    acc[lm][nt] = __builtin_amdgcn_mfma_f32_16x16x32_bf16(
                        af, bf[nt], acc[lm][nt], 0, 0, 0);
            }
        };

        bf16x8 bufA[NTW], bufB[NTW];
        loadB(bufA, 0);
        #pragma unroll 1
        for (int it = 0; it < 18; it += 2) {
            loadB(bufB, it + 1);
            compute(bufA, it);
            if (it + 2 < 18) loadB(bufA, it + 2);
            compute(bufB, it + 1);
        }
    }

    float bv[NTW], msum[NTW];
    #pragma unroll
    for (int nt = 0; nt < NTW; ++nt) {
        int co = (n_base + nt) * 16 + li;
        bv[nt] = (co < Cout) ? bias[co] : 0.f;
        msum[nt] = 0.f;
    }

    #pragma unroll
    for (int lm = 0; lm < LM; ++lm) {
        int row = row0 + m_base + lm;
        #pragma unroll
        for (int r = 0; r < 4; ++r) {
            int col = col0 + lq * 4 + r;
            size_t pbase = (inb + row * 128 + col) * (size_t)Coutp;
            #pragma unroll
            for (int nt = 0; nt < NTW; ++nt) {
                float v = acc[lm][nt][r] + bv[nt];
                if (relu) v = fmaxf(v, 0.f);
                if (DOMEAN) msum[nt] += v;
                out[pbase + (n_base + nt) * 16 + li] = f2bf(v);
            }
        }
    }
    if (DOMEAN) {
        #pragma unroll
        for (int nt = 0; nt < NTW; ++nt) {
            float t = msum[nt];
            t += __shfl_xor(t, 16, 64);
            t += __shfl_xor(t, 32, 64);
            if (lq == 0)
                atomicAdd(&meanb[b * 128 + (n_base + nt) * 16 + li], t);
        }
    }
}

// ---------------- SE-scaled conv (separate function: codegen decoupled) -----
// SCALEA hardwired: sl[128] per-block prologue (wave-parallel), applied
// during A staging. TAILFUSE: dynfilter fusion (MFMA e-GEMM), final output.
template <int LM, int NTW, int WNSPLIT, int DOMEAN, int TAILFUSE>
__global__ __launch_bounds__(256, 2) void conv_mfma_se(
    const unsigned short* __restrict__ in, const unsigned short* __restrict__ wT,
    const float* __restrict__ bias, unsigned short* __restrict__ out,
    float* __restrict__ meanb, const float* __restrict__ se_mean,
    const float* __restrict__ sw1, const float* __restrict__ sb1,
    const float* __restrict__ sw2, const float* __restrict__ sb2,
    const float* __restrict__ x, const unsigned short* __restrict__ kb,
    float* __restrict__ outf, int Coutp, int Cout, int relu)
{
    __shared__ unsigned short lds[TAILFUSE ? 26624 : 20736];
    __shared__ float slds[136];          // [0:128) sigmoid scales, [128:136) h1
    const int tid = threadIdx.x;
    const int b = blockIdx.y;
    const int row0 = (blockIdx.x >> 3) << 4;
    const int col0 = (blockIdx.x & 7) << 4;
    const int l = tid & 63, wv = tid >> 6;
    const int li = l & 15, lq = l >> 4;
    const int m_base = WNSPLIT ? (wv >> 1) * LM : wv * LM;
    const int n_base = WNSPLIT ? (wv & 1) * NTW : 0;
    const size_t inb = ((size_t)b) << 14;
    const unsigned short* wbase = wT;

    // ---- wave-parallel SE prologue: 8 groups of 32 lanes, one dot each ----
    {
        const int grp = tid >> 5, j = tid & 31;
        float4 wv4 = ((const float4*)(sw1 + grp * 128))[j];
        float4 mv4 = ((const float4*)(se_mean + b * 128))[j];
        float part = wv4.x * mv4.x + wv4.y * mv4.y + wv4.z * mv4.z + wv4.w * mv4.w;
        part += __shfl_xor(part, 1, 64);
        part += __shfl_xor(part, 2, 64);
        part += __shfl_xor(part, 4, 64);
        part += __shfl_xor(part, 8, 64);
        part += __shfl_xor(part, 16, 64);
        if (j == 0)
            slds[128 + grp] = fmaxf(part * (1.f / 16384.f) + sb1[grp], 0.f);
    }
    __syncthreads();
    if (tid < 128) {
        float s = sb2[tid];
        #pragma unroll
        for (int j = 0; j < 8; ++j) s += sw2[tid * 8 + j] * slds[128 + j];
        slds[tid] = 1.f / (1.f + expf(-s));
    }
    __syncthreads();

    f32x4 acc[LM][NTW];
    #pragma unroll
    for (int lm = 0; lm < LM; ++lm)
        #pragma unroll
        for (int nt = 0; nt < NTW; ++nt)
            acc[lm][nt] = (f32x4){0.f, 0.f, 0.f, 0.f};

    #pragma unroll 1
    for (int half = 0; half < 2; ++half) {
        float msc[8];
        #pragma unroll
        for (int j = 0; j < 8; ++j)
            msc[j] = slds[half * 64 + (tid & 7) * 8 + j];
        __syncthreads();
        for (int u = tid; u < 2592; u += 256) {   // 324 px * 8 ch-groups
            int px = u >> 3, g = u & 7;
            int hr = px / 18, hc = px - hr * 18;
            int gy = row0 - 1 + hr, gx = col0 - 1 + hc;
            bf16x8 v = {0, 0, 0, 0, 0, 0, 0, 0};
            if ((unsigned)gy < 128u && (unsigned)gx < 128u)
                v = *(const bf16x8*)(in + ((inb + (gy << 7) + gx) << 7) + half * 64 + g * 8);
            #pragma unroll
            for (int j = 0; j < 8; ++j)
                v[j] = (short)f2bf(bf2f((unsigned short)v[j]) * msc[j]);
            int p = g ^ (px & 7);                 // XOR swizzle
            *(bf16x8*)(lds + px * 64 + p * 8) = v;
        }
        __syncthreads();

        auto loadB = [&](bf16x8 (&dst)[NTW], int s) {
            int tap = s >> 1, kcl = s & 1;
            const unsigned short* p = wbase +
                (size_t)(tap * 4 + half * 2 + kcl) * (Coutp * 32) +
                (n_base * 16 + li) * 32 + lq * 8;
            #pragma unroll
            for (int nt = 0; nt < NTW; ++nt)
                dst[nt] = *(const bf16x8*)(p + nt * 512);
        };
        auto compute = [&](bf16x8 (&bf)[NTW], int s) {
            int tap = s >> 1, kcl = s & 1;
            int ky = tap / 3, kx = tap - ky * 3;
            int g = kcl * 4 + lq;
            #pragma unroll
            for (int lm = 0; lm < LM; ++lm) {
                int px = (m_base + lm + ky) * 18 + li + kx;
                bf16x8 af = *(const bf16x8*)(lds + px * 64 + ((g ^ (px & 7)) * 8));
                #pragma unroll
                for (int nt = 0; nt < NTW; ++nt)
                    acc[lm][nt] = __builtin_amdgcn_mfma_f32_16x16x32_bf16(
                        af, bf[nt], acc[lm][nt], 0, 0, 0);
            }
        };

        bf16x8 bufA[NTW], bufB[NTW];
        loadB(bufA, 0);
        #pragma unroll 1
        for (int it = 0; it < 18; it += 2) {
            loadB(bufB, it + 1);
            compute(bufA, it);
            if (it + 2 < 18) loadB(bufA, it + 2);
            compute(bufB, it + 1);
        }
    }

    float bv[NTW], msum[NTW];
    #pragma unroll
    for (int nt = 0; nt < NTW; ++nt) {
        int co = (n_base + nt) * 16 + li;
        bv[nt] = (co < Cout) ? bias[co] : 0.f;
        msum[nt] = 0.f;
    }

    if (TAILFUSE) {
        // ---- P (wgt) -> LDS, stride 104 ush; zero pad co 80..95 ----
        __syncthreads();
        #pragma unroll
        for (int lm = 0; lm < LM; ++lm) {
            int rowl = m_base + lm;
            #pragma unroll
            for (int r = 0; r < 4; ++r) {
                int coll = lq * 4 + r;
                #pragma unroll
                for (int nt = 0; nt < NTW; ++nt)
                    lds[(rowl * 16 + coll) * 104 + nt * 16 + li] =
                        f2bf(acc[lm][nt][r] + bv[nt]);
            }
        }
        {
            bf16x8 z = {0, 0, 0, 0, 0, 0, 0, 0};
            *(bf16x8*)(lds + tid * 104 + 80) = z;
            *(bf16x8*)(lds + tid * 104 + 88) = z;
        }
        __syncthreads();

        // ---- e-GEMM: e[px][i] = sum_co P[px][co] * kern[co][i] ----
        f32x4 eacc[4][2];
        #pragma unroll
        for (int mm = 0; mm < 4; ++mm)
            #pragma unroll
            for (int nt = 0; nt < 2; ++nt)
                eacc[mm][nt] = (f32x4){0.f, 0.f, 0.f, 0.f};
        #pragma unroll
        for (int s = 0; s < 3; ++s) {
            bf16x8 kbf[2];
            #pragma unroll
            for (int nt = 0; nt < 2; ++nt)
                kbf[nt] = *(const bf16x8*)(kb + ((s * 2 + nt) * 16 + li) * 32 + lq * 8);
            #pragma unroll
            for (int mm = 0; mm < 4; ++mm) {
                int px = (wv * 4 + mm) * 16 + li;
                bf16x8 pf = *(const bf16x8*)(lds + px * 104 + s * 32 + lq * 8);
                #pragma unroll
                for (int nt = 0; nt < 2; ++nt)
                    eacc[mm][nt] = __builtin_amdgcn_mfma_f32_16x16x32_bf16(
                        pf, kbf[nt], eacc[mm][nt], 0, 0, 0);
            }
        }
        __syncthreads();

        // ---- e (C-layout) -> LDS fp32, stride 33 ----
        float* elds = (float*)lds;
        #pragma unroll
        for (int mm = 0; mm < 4; ++mm) {
            #pragma unroll
            for (int nt = 0; nt < 2; ++nt) {
                int i = nt * 16 + li;
                if (i < 25) {
                    #pragma unroll
                    for (int r = 0; r < 4; ++r) {
                        int px = (wv * 4 + mm) * 16 + lq * 4 + r;
                        elds[px * 33 + i] = eacc[mm][nt][r];
                    }
                }
            }
        }
        __syncthreads();

        // ---- apply ----
        const int h = row0 + (tid >> 4), w = col0 + (tid & 15);
        const int pix = h * 128 + w;
        float e[25];
        #pragma unroll
        for (int i = 0; i < 25; ++i) e[i] = elds[tid * 33 + i];

        int yy[5], xx[5];
        #pragma unroll
        for (int d = 0; d < 5; ++d) {
            int y = h - 2 + d;
            yy[d] = y < 0 ? -y : (y > 127 ? 254 - y : y);
            int xv = w - 2 + d;
            xx[d] = xv < 0 ? -xv : (xv > 127 ? 254 - xv : xv);
        }
        #pragma unroll
        for (int c = 0; c < 3; ++c) {
            const float* xc = x + ((size_t)(b * 3 + c) << 14);
            float s = 0.f;
            #pragma unroll
            for (int dy = 0; dy < 5; ++dy)
                #pragma unroll
                for (int dx = 0; dx < 5; ++dx)
                    s += e[dy * 5 + dx] * xc[yy[dy] * 128 + xx[dx]];
            outf[((size_t)(b * 3 + c) << 14) + pix] = s;
        }
        return;
    }

    #pragma unroll
    for (int lm = 0; lm < LM; ++lm) {
        int row = row0 + m_base + lm;
        #pragma unroll
        for (int r = 0; r < 4; ++r) {
            int col = col0 + lq * 4 + r;
            size_t pbase = (inb + row * 128 + col) * (size_t)Coutp;
            #pragma unroll
            for (int nt = 0; nt < NTW; ++nt) {
                float v = acc[lm][nt][r] + bv[nt];
                if (relu) v = fmaxf(v, 0.f);
                if (DOMEAN) msum[nt] += v;
                out[pbase + (n_base + nt) * 16 + li] = f2bf(v);
            }
        }
    }
    if (DOMEAN) {
        #pragma unroll
        for (int nt = 0; nt < NTW; ++nt) {
            float t = msum[nt];
            t += __shfl_xor(t, 16, 64);
            t += __shfl_xor(t, 32, 64);
            if (lq == 0)
                atomicAdd(&meanb[b * 128 + (n_base + nt) * 16 + li], t);
        }
    }
}

// ---------------------------------------------------------------------------
extern "C" void kernel_launch(void* const* d_in, const int* in_sizes, int n_in,
                              void* d_out, int out_size, void* d_ws, size_t ws_size,
                              hipStream_t stream)
{
    const float* x      = (const float*)d_in[0];
    const float* w_head = (const float*)d_in[1];
    const float* b_head = (const float*)d_in[2];
    const float* w_h1a  = (const float*)d_in[3];
    const float* b_h1a  = (const float*)d_in[4];
    const float* w_h1b  = (const float*)d_in[5];
    const float* b_h1b  = (const float*)d_in[6];
    const float* du1_w1 = (const float*)d_in[7];
    const float* du1_b1 = (const float*)d_in[8];
    const float* du1_w2 = (const float*)d_in[9];
    const float* du1_b2 = (const float*)d_in[10];
    const float* w_h2a  = (const float*)d_in[11];
    const float* b_h2a  = (const float*)d_in[12];
    const float* w_h2b  = (const float*)d_in[13];
    const float* b_h2b  = (const float*)d_in[14];
    const float* du2_w1 = (const float*)d_in[15];
    const float* du2_b1 = (const float*)d_in[16];
    const float* du2_w2 = (const float*)d_in[17];
    const float* du2_b2 = (const float*)d_in[18];
    const float* w_tail = (const float*)d_in[19];
    const float* b_tail = (const float*)d_in[20];
    const float* kern   = (const float*)d_in[21];
    float* out = (float*)d_out;

    unsigned short* fb0  = (unsigned short*)d_ws;        // 16,777,216 elems
    unsigned short* fb1  = fb0 + 16777216;
    unsigned short* wt1  = fb1 + 16777216;               // 147456 each
    unsigned short* wt2  = wt1 + 147456;
    unsigned short* wt3  = wt2 + 147456;
    unsigned short* wt4  = wt3 + 147456;
    unsigned short* wtt  = wt4 + 147456;                 // 92160
    unsigned short* kbb  = wtt + 92160;                  // 3072 (kern B-frag)
    float* mean1  = (float*)(kbb + 3072);                // 1024
    float* mean2  = mean1 + 1024;

    dim3 blk(256);
    // prep: head conv (2048) + coalesced wtrans (74) + kb/means (1)
    prep<<<dim3(2123), blk, 0, stream>>>(x, w_head, b_head, fb0,
                                         w_h1a, w_h1b, w_h2a, w_h2b, w_tail,
                                         kern, wt1, wt2, wt3, wt4, wtt, kbb,
                                         mean1);

    dim3 cgrid(64, 8);   // 512 blocks: 64 tiles/batch x 8 batches
    conv_mfma<8, 4, 1, 0><<<cgrid, blk, 0, stream>>>(
        fb0, wt1, 0, b_h1a, fb1, nullptr, nullptr, nullptr, nullptr, 128, 128, 1);
    conv_mfma<8, 4, 1, 1><<<cgrid, blk, 0, stream>>>(
        fb1, wt2, 0, b_h1b, fb0, mean1, nullptr, nullptr, nullptr, 128, 128, 1);

    // h2a: SE1 scale applied to staged A (reads mean1 + du1 params)
    conv_mfma_se<8, 4, 1, 0, 0><<<cgrid, blk, 0, stream>>>(
        fb0, wt3, b_h2a, fb1, nullptr, mean1, du1_w1, du1_b1, du1_w2, du1_b2,
        nullptr, nullptr, nullptr, 128, 128, 1);
    conv_mfma<8, 4, 1, 1><<<cgrid, blk, 0, stream>>>(
        fb1, wt4, 0, b_h2b, fb0, mean2, nullptr, nullptr, nullptr, 128, 128, 1);

    // tail conv (SE2 scale on staged A) + fused dynamic filter e-GEMM
    conv_mfma_se<4, 5, 0, 0, 1><<<cgrid, blk, 0, stream>>>(
        fb0, wtt, b_tail, nullptr, nullptr, mean2, du2_w1, du2_b1, du2_w2,
        du2_b2, x, kbb, out, 80, 72, 0);
}